// Round 4
// baseline (107.645 us; speedup 1.0000x reference)
//
#include <hip/hip_runtime.h>
#include <hip/hip_bf16.h>

#define NL  128   // layers (n)
#define DK  256   // d_in (k)
#define DO_ 256   // d_out (o)
#define MB  1024  // batch (m)

typedef __attribute__((ext_vector_type(4))) float f32x4;
typedef __attribute__((ext_vector_type(8))) short bf16x8;
typedef __attribute__((ext_vector_type(8))) unsigned short u16x8;

static __device__ __forceinline__ unsigned short f2bf(float f) {
  __hip_bfloat16 h = __float2bfloat16(f);
  return __builtin_bit_cast(unsigned short, h);
}

// ---------------------------------------------------------------------------
// Prep: W[n][k][o] fp32 -> Wt in MFMA B-fragment order, bf16:
//   unit (o, kc[8-k chunk]) -> ob=o>>4, lrow=o&15, s=kc>>2, lhi=kc&3
//   elem offset = ((n*16+ob)*8 + s)*512 + (lhi*16+lrow)*8 + (k&7)
// so a wave's B-load for (ob, s) is ONE contiguous 1KB dwordx4 per lane.
// ---------------------------------------------------------------------------
__global__ __launch_bounds__(256) void wt_prep(const float* __restrict__ W,
                                               unsigned short* __restrict__ Wt) {
  const int n     = blockIdx.y;
  const int ktile = (blockIdx.x >> 2) * 64;
  const int otile = (blockIdx.x & 3) * 64;
  __shared__ float tile[64][65];  // +1 pad: conflict-free column reads
  const float* Wn = W + (size_t)n * DK * DO_;
  const int t  = threadIdx.x;
  const int lr = t >> 4;
  const int lc = (t & 15) * 4;
#pragma unroll
  for (int p = 0; p < 4; ++p) {
    const int k = p * 16 + lr;
    const float4 v = *(const float4*)(Wn + (size_t)(ktile + k) * DO_ + otile + lc);
    tile[k][lc + 0] = v.x; tile[k][lc + 1] = v.y;
    tile[k][lc + 2] = v.z; tile[k][lc + 3] = v.w;
  }
  __syncthreads();
  const int ol = t >> 2;            // local o 0..63
  const int o  = otile + ol;
  const int kq = t & 3;
  unsigned short* Wt_n = Wt + (size_t)n * DO_ * DK;
#pragma unroll
  for (int h = 0; h < 2; ++h) {
    u16x8 w;
#pragma unroll
    for (int j = 0; j < 8; ++j) w[j] = f2bf(tile[kq * 16 + h * 8 + j][ol]);
    const int kc = (ktile >> 3) + kq * 2 + h;   // global 8-k chunk id (0..31)
    const int ob = o >> 4, lrw = o & 15, s = kc >> 2, lh = kc & 3;
    *(u16x8*)(Wt_n + ((size_t)(ob * 8 + s) * 64 + lh * 16 + lrw) * 8) = w;
  }
}

// ---------------------------------------------------------------------------
// Main: block = (n, 128-row m-group), 4-tile M-loop pipeline, dbuf 16KB LDS.
// Per iter: issue next-tile loads -> convert+write cur (vmcnt waits only cur)
// -> lgkmcnt(0) + RAW s_barrier (no vmcnt drain!) -> 64 MFMA/wave + stores.
// Operand-swapped MFMA: lane acc = 4 contiguous o -> float4 stores.
// XCD swizzle: bid%8 == xcd gets n in [xcd*16, +16) -> Wt L2-resident (2MB).
// ---------------------------------------------------------------------------
__global__ __launch_bounds__(256, 3) void nlinear_mfma(
    const float* __restrict__ X, const unsigned short* __restrict__ Wt,
    const float* __restrict__ bias, float* __restrict__ out) {
  const int wid  = blockIdx.x;
  const int n    = (wid & 7) * 16 + ((wid >> 3) & 15);
  const int mg   = wid >> 7;          // 0..7, 128 rows each
  const int t    = threadIdx.x;
  const int wave = t >> 6;            // o-wave: 64 o each
  const int lane = t & 63;
  const int lrow = lane & 15;
  const int lhi  = lane >> 4;

  __shared__ unsigned short Alds[2][32 * 256];  // 2 x 16KB, swizzled

  // staging: thread owns (row = t&31, 32-k chunk = t>>5); 128B contiguous/thread
  const int srow = t & 31;
  const int skq  = t >> 5;
  const float* xsrc = X + ((size_t)(mg * 128 + srow) * NL + n) * DK + skq * 32;

  const unsigned short* Wn = Wt + (size_t)n * DO_ * DK;
  const float* bb = bias + n * DO_ + wave * 64 + lhi * 4;

  f32x4 sv[2][8];
#pragma unroll
  for (int j = 0; j < 8; ++j) sv[0][j] = *(const f32x4*)(xsrc + j * 4);

#pragma unroll
  for (int tt = 0; tt < 4; ++tt) {
    const int cb = tt & 1;
    // issue next tile's loads FIRST; they stay in flight across this iter
    if (tt < 3) {
      const float* nx = xsrc + (size_t)(tt + 1) * 32 * NL * DK;
#pragma unroll
      for (int j = 0; j < 8; ++j) sv[cb ^ 1][j] = *(const f32x4*)(nx + j * 4);
    }
    // convert + write current tile (compiler waits vmcnt only for sv[cb])
    {
      char* ab = (char*)Alds[cb];
#pragma unroll
      for (int cc = 0; cc < 4; ++cc) {
        u16x8 w;
        const f32x4 a0 = sv[cb][cc * 2], a1 = sv[cb][cc * 2 + 1];
#pragma unroll
        for (int e = 0; e < 4; ++e) { w[e] = f2bf(a0[e]); w[4 + e] = f2bf(a1[e]); }
        *(u16x8*)(ab + srow * 512 + (((skq * 4 + cc) ^ (srow & 7)) << 4)) = w;
      }
    }
    // LDS writes visible, then RAW barrier — no vmcnt(0) drain (keeps nxt flying)
    asm volatile("s_waitcnt lgkmcnt(0)" ::: "memory");
    __builtin_amdgcn_s_barrier();
    __builtin_amdgcn_sched_barrier(0);

    f32x4 acc[2][4];
#pragma unroll
    for (int mi = 0; mi < 2; ++mi)
#pragma unroll
      for (int oj = 0; oj < 4; ++oj) acc[mi][oj] = (f32x4){0.f, 0.f, 0.f, 0.f};

    const char* ab = (const char*)Alds[cb];
#pragma unroll
    for (int s = 0; s < 8; ++s) {
      bf16x8 bfr[4], af[2];
#pragma unroll
      for (int oj = 0; oj < 4; ++oj)   // wave-contiguous 1KB load (prefragmented)
        bfr[oj] = *(const bf16x8*)(Wn + ((size_t)((wave * 4 + oj) * 8 + s) * 64 + lane) * 8);
#pragma unroll
      for (int mi = 0; mi < 2; ++mi)
        af[mi] = *(const bf16x8*)(ab + (mi * 16 + lrow) * 512 +
                                  (((s * 4 + lhi) ^ (lrow & 7)) << 4));
#pragma unroll
      for (int oj = 0; oj < 4; ++oj)
#pragma unroll
        for (int mi = 0; mi < 2; ++mi)   // SWAPPED: D[o][m], lane regs = 4 contig o
          acc[mi][oj] = __builtin_amdgcn_mfma_f32_16x16x32_bf16(
              bfr[oj], af[mi], acc[mi][oj], 0, 0, 0);
    }
    // epilogue: m = lane&15, o = wave*64 + oj*16 + lhi*4 + r  -> float4 stores
#pragma unroll
    for (int mi = 0; mi < 2; ++mi) {
      const int m = mg * 128 + tt * 32 + mi * 16 + lrow;
      float* orow = out + ((size_t)m * NL + n) * DO_ + wave * 64 + lhi * 4;
#pragma unroll
      for (int oj = 0; oj < 4; ++oj) {
        const f32x4 bv = *(const f32x4*)(bb + oj * 16);
        *(f32x4*)(orow + oj * 16) = acc[mi][oj] + bv;
      }
    }
  }
}

// ---------------------------------------------------------------------------
// Fallback (only if ws too small for Wt): plain fp32, correct but slow.
// ---------------------------------------------------------------------------
__global__ __launch_bounds__(256) void nlinear_naive(
    const float* __restrict__ X, const float* __restrict__ W,
    const float* __restrict__ B, float* __restrict__ out) {
  const int n = blockIdx.y;
  const int m = blockIdx.x;
  const int o = threadIdx.x;
  __shared__ float xs[DK];
  xs[o] = X[((size_t)m * NL + n) * DK + o];
  __syncthreads();
  const float* Wn = W + (size_t)n * DK * DO_;
  float s = B[n * DO_ + o];
  for (int k = 0; k < DK; ++k) s = fmaf(xs[k], Wn[(size_t)k * DO_ + o], s);
  out[((size_t)m * NL + n) * DO_ + o] = s;
}

extern "C" void kernel_launch(void* const* d_in, const int* in_sizes, int n_in,
                              void* d_out, int out_size, void* d_ws, size_t ws_size,
                              hipStream_t stream) {
  const float* x = (const float*)d_in[0];
  const float* w = (const float*)d_in[1];
  const float* b = (const float*)d_in[2];
  float* out     = (float*)d_out;
  const size_t wt_bytes = (size_t)NL * DK * DO_ * sizeof(unsigned short);
  if (ws_size >= wt_bytes) {
    unsigned short* wt = (unsigned short*)d_ws;
    wt_prep<<<dim3(16, NL), 256, 0, stream>>>(w, wt);
    nlinear_mfma<<<dim3(1024), 256, 0, stream>>>(x, wt, b, out);
  } else {
    nlinear_naive<<<dim3(MB, NL), 256, 0, stream>>>(x, w, b, out);
  }
}

// Round 5
// 87.099 us; speedup vs baseline: 1.2359x; 1.2359x over previous
//
#include <hip/hip_runtime.h>
#include <hip/hip_bf16.h>

#define NL  128   // layers (n)
#define DK  256   // d_in (k)
#define DO_ 256   // d_out (o)
#define MB  1024  // batch (m)

typedef __attribute__((ext_vector_type(4))) float f32x4;
typedef __attribute__((ext_vector_type(8))) short bf16x8;
typedef __attribute__((ext_vector_type(8))) unsigned short u16x8;
typedef __attribute__((ext_vector_type(4))) unsigned short u16x4;

static __device__ __forceinline__ unsigned short f2bf(float f) {
  __hip_bfloat16 h = __float2bfloat16(f);
  return __builtin_bit_cast(unsigned short, h);
}

// ---------------------------------------------------------------------------
// Prep: W[n][k][o] fp32 -> Wt in MFMA B-fragment order, bf16 (verified R4):
//   unit (o, kc[8-k chunk]) -> ob=o>>4, lrow=o&15, s=kc>>2, lhi=kc&3
//   elem offset = ((n*16+ob)*8 + s)*512 + (lhi*16+lrow)*8 + (k&7)
// so a wave's B-load for (ob, s) is ONE contiguous 1KB dwordx4 per lane.
// ---------------------------------------------------------------------------
__global__ __launch_bounds__(256) void wt_prep(const float* __restrict__ W,
                                               unsigned short* __restrict__ Wt) {
  const int n     = blockIdx.y;
  const int ktile = (blockIdx.x >> 2) * 64;
  const int otile = (blockIdx.x & 3) * 64;
  __shared__ float tile[64][65];  // +1 pad: conflict-free column reads
  const float* Wn = W + (size_t)n * DK * DO_;
  const int t  = threadIdx.x;
  const int lr = t >> 4;
  const int lc = (t & 15) * 4;
#pragma unroll
  for (int p = 0; p < 4; ++p) {
    const int k = p * 16 + lr;
    const float4 v = *(const float4*)(Wn + (size_t)(ktile + k) * DO_ + otile + lc);
    tile[k][lc + 0] = v.x; tile[k][lc + 1] = v.y;
    tile[k][lc + 2] = v.z; tile[k][lc + 3] = v.w;
  }
  __syncthreads();
  const int ol = t >> 2;            // local o 0..63
  const int o  = otile + ol;
  const int kq = t & 3;
  unsigned short* Wt_n = Wt + (size_t)n * DO_ * DK;
#pragma unroll
  for (int h = 0; h < 2; ++h) {
    u16x8 w;
#pragma unroll
    for (int j = 0; j < 8; ++j) w[j] = f2bf(tile[kq * 16 + h * 8 + j][ol]);
    const int kc = (ktile >> 3) + kq * 2 + h;   // global 8-k chunk id (0..31)
    const int ob = o >> 4, lrw = o & 15, s = kc >> 2, lh = kc & 3;
    *(u16x8*)(Wt_n + ((size_t)(ob * 8 + s) * 64 + lh * 16 + lrw) * 8) = w;
  }
}

// ---------------------------------------------------------------------------
// Main: 4096 independent one-shot blocks (BM=32). Per block:
//  stage: wave w, iter j -> x row (mg*32 + w*8 + j), lane takes k=lane*4:
//         ONE 1KB transaction per load instr; bf16 -> swizzled LDS via
//         conflict-free same-row ds_write_b64 at slot (lane>>1)^j.
//  ONE barrier. compute: 8 s x {4 coalesced B-loads (L2-resident prefrag Wt),
//  2 LDS b128 reads, 8 swapped MFMA}. float4 bias + float4 stores.
// XCD swizzle: bid&7 -> n in [xcd*16,+16): 2MB Wt slice per XCD L2.
// ---------------------------------------------------------------------------
__global__ __launch_bounds__(256, 4) void nlinear_mfma(
    const float* __restrict__ X, const unsigned short* __restrict__ Wt,
    const float* __restrict__ bias, float* __restrict__ out) {
  const int wid  = blockIdx.x;
  const int n    = (wid & 7) * 16 + ((wid >> 3) & 15);
  const int mg   = wid >> 7;          // 0..31
  const int t    = threadIdx.x;
  const int wave = t >> 6;            // o-wave: 64 o each
  const int lane = t & 63;
  const int lrow = lane & 15;
  const int lhi  = lane >> 4;
  const int mbase = mg * 32;

  __shared__ unsigned short Alds[32 * 256];  // 16 KB, 512B rows, swizzled 16B slots

  // ---- stage: 8 fully-coalesced row loads per wave ----
  const float* xw = X + ((size_t)(mbase + wave * 8) * NL + n) * DK + lane * 4;
  f32x4 xv[8];
#pragma unroll
  for (int j = 0; j < 8; ++j)
    xv[j] = *(const f32x4*)(xw + (size_t)j * NL * DK);

  char* ab = (char*)Alds;
#pragma unroll
  for (int j = 0; j < 8; ++j) {
    u16x4 h;
#pragma unroll
    for (int e = 0; e < 4; ++e) h[e] = f2bf(xv[j][e]);
    // row = wave*8+j; chunk c = lane>>1; slot = c ^ (row&7) = c ^ j; sub = (lane&1)*8
    *(u16x4*)(ab + (wave * 8 + j) * 512 + (((lane >> 1) ^ j) << 4) + (lane & 1) * 8) = h;
  }
  __syncthreads();  // the only barrier

  const unsigned short* Wn = Wt + (size_t)n * DO_ * DK;
  const float* bb = bias + n * DO_ + wave * 64 + lhi * 4;
  f32x4 bv[4];
#pragma unroll
  for (int oj = 0; oj < 4; ++oj) bv[oj] = *(const f32x4*)(bb + oj * 16);

  f32x4 acc[2][4];
#pragma unroll
  for (int mi = 0; mi < 2; ++mi)
#pragma unroll
    for (int oj = 0; oj < 4; ++oj) acc[mi][oj] = (f32x4){0.f, 0.f, 0.f, 0.f};

#pragma unroll
  for (int s = 0; s < 8; ++s) {
    bf16x8 bfr[4], af[2];
#pragma unroll
    for (int oj = 0; oj < 4; ++oj)  // wave-contiguous 1KB load (prefragmented)
      bfr[oj] = *(const bf16x8*)(Wn + ((size_t)((wave * 4 + oj) * 8 + s) * 64 + lane) * 8);
#pragma unroll
    for (int mi = 0; mi < 2; ++mi) {
      const int row = mi * 16 + lrow;
      af[mi] = *(const bf16x8*)(ab + row * 512 + (((s * 4 + lhi) ^ (row & 7)) << 4));
    }
#pragma unroll
    for (int oj = 0; oj < 4; ++oj)
#pragma unroll
      for (int mi = 0; mi < 2; ++mi)  // SWAPPED: D[o][m], lane regs = 4 contig o
        acc[mi][oj] = __builtin_amdgcn_mfma_f32_16x16x32_bf16(
            bfr[oj], af[mi], acc[mi][oj], 0, 0, 0);
  }

  // epilogue: m = lane&15 (+mi*16), o = wave*64 + oj*16 + lhi*4 + r -> float4
#pragma unroll
  for (int mi = 0; mi < 2; ++mi) {
    const int m = mbase + mi * 16 + lrow;
    float* orow = out + ((size_t)m * NL + n) * DO_ + wave * 64 + lhi * 4;
#pragma unroll
    for (int oj = 0; oj < 4; ++oj)
      *(f32x4*)(orow + oj * 16) = acc[mi][oj] + bv[oj];
  }
}

// ---------------------------------------------------------------------------
// Fallback (only if ws too small for Wt): plain fp32, correct but slow.
// ---------------------------------------------------------------------------
__global__ __launch_bounds__(256) void nlinear_naive(
    const float* __restrict__ X, const float* __restrict__ W,
    const float* __restrict__ B, float* __restrict__ out) {
  const int n = blockIdx.y;
  const int m = blockIdx.x;
  const int o = threadIdx.x;
  __shared__ float xs[DK];
  xs[o] = X[((size_t)m * NL + n) * DK + o];
  __syncthreads();
  const float* Wn = W + (size_t)n * DK * DO_;
  float s = B[n * DO_ + o];
  for (int k = 0; k < DK; ++k) s = fmaf(xs[k], Wn[(size_t)k * DO_ + o], s);
  out[((size_t)m * NL + n) * DO_ + o] = s;
}

extern "C" void kernel_launch(void* const* d_in, const int* in_sizes, int n_in,
                              void* d_out, int out_size, void* d_ws, size_t ws_size,
                              hipStream_t stream) {
  const float* x = (const float*)d_in[0];
  const float* w = (const float*)d_in[1];
  const float* b = (const float*)d_in[2];
  float* out     = (float*)d_out;
  const size_t wt_bytes = (size_t)NL * DK * DO_ * sizeof(unsigned short);
  if (ws_size >= wt_bytes) {
    unsigned short* wt = (unsigned short*)d_ws;
    wt_prep<<<dim3(16, NL), 256, 0, stream>>>(w, wt);
    nlinear_mfma<<<dim3(4096), 256, 0, stream>>>(x, wt, b, out);
  } else {
    nlinear_naive<<<dim3(MB, NL), 256, 0, stream>>>(x, w, b, out);
  }
}